// Round 8
// baseline (168.295 us; speedup 1.0000x reference)
//
#include <hip/hip_runtime.h>

constexpr int BB = 16;     // batch
constexpr int CC = 512;    // channels
constexpr int PP = 32;     // clusters
constexpr int NN = 4096;   // H*W
constexpr int TN = 64;     // fused n-tile per block
constexpr int CH = 128;    // c-chunk

using f32x4 = __attribute__((ext_vector_type(4))) float;
using bf16x8 = __attribute__((ext_vector_type(8))) short;
typedef unsigned int uint;

__device__ __forceinline__ ushort f2bf(float f) {
  unsigned u = __builtin_bit_cast(unsigned, f);
  u += 0x7FFFu + ((u >> 16) & 1u);   // round-to-nearest-even
  return (ushort)(u >> 16);
}

// pack float -> (bf16_lo << 16) | bf16_hi, hi = bf16(f), lo = bf16(f - hi)
__device__ __forceinline__ uint packbf(float f) {
  uint u = __builtin_bit_cast(uint, f);
  uint hi = (u + (0x7FFFu + ((u >> 16) & 1u))) >> 16;
  float hif = __builtin_bit_cast(float, hi << 16);
  float lof = f - hif;
  uint ul = __builtin_bit_cast(uint, lof);
  uint lo = (ul + (0x7FFFu + ((ul >> 16) & 1u))) >> 16;
  return (lo << 16) | hi;
}

struct BfPair { bf16x8 hi, lo; };

__device__ __forceinline__ BfPair unpack8(const uint* __restrict__ row, int co) {
  uint4 a = *(const uint4*)(row + co);
  uint4 b = *(const uint4*)(row + co + 4);
  union { bf16x8 v; uint d[4]; } H, L;
  H.d[0] = (a.x & 0xffffu) | (a.y << 16); L.d[0] = (a.x >> 16) | (a.y & 0xffff0000u);
  H.d[1] = (a.z & 0xffffu) | (a.w << 16); L.d[1] = (a.z >> 16) | (a.w & 0xffff0000u);
  H.d[2] = (b.x & 0xffffu) | (b.y << 16); L.d[2] = (b.x >> 16) | (b.y & 0xffff0000u);
  H.d[3] = (b.z & 0xffffu) | (b.w << 16); L.d[3] = (b.z >> 16) | (b.w & 0xffff0000u);
  return {H.v, L.v};
}

// ---------------------------------------------------------------------------
// prep: beta = sigmoid(sf), rbeta = 1/beta, csq[p] = |centers_p|^2 (fp32).
// (sum_ass + qx zeroing handled by hipMemsetAsync.)
// ---------------------------------------------------------------------------
__global__ __launch_bounds__(64) void prep_kernel(
    const float* __restrict__ w, const float* __restrict__ sf,
    float* __restrict__ beta, float* __restrict__ rbeta,
    float* __restrict__ csq) {
  int p = blockIdx.x;
  int t = threadIdx.x;
  float s = 0.f;
  for (int i = t; i < CC; i += 64) {
    float v = w[p * CC + i];
    s = fmaf(v, v, s);
  }
#pragma unroll
  for (int off = 32; off; off >>= 1) s += __shfl_down(s, off);
  if (t == 0) {
    csq[p] = s;
    float e = __expf(-sf[p]);
    rbeta[p] = 1.f + e;            // 1/beta
    beta[p] = 1.f / (1.f + e);     // beta
  }
}

// ---------------------------------------------------------------------------
// fused assign+qx. grid 1024 (16 b x 64 n-tiles of 64), block 512 = 8 waves.
// Phase 1 (assign): cx = cent·x via split-bf16 MFMA (hi*hi+hi*lo+lo*hi).
//   Waves split each 128-c chunk in half (k-parallel); pair (wv, wv+4)
//   reduce partial acc via LDS. Softmax in-register (shfl_xor 16/32).
//   While staging, also keep bf16-hi x in xh[c][n] for phase 2.
// Phase 2 (qx): qx[b][p][c] += a[p][n]·xh[c][n] via bf16 MFMA over this
//   tile's 64 n; fp32 atomicAdd into L2-resident qx (zeroed by memset).
// ---------------------------------------------------------------------------
__global__ __launch_bounds__(512) void fused_kernel(
    const float* __restrict__ x, const float* __restrict__ w,
    const float* __restrict__ rbeta_, const float* __restrict__ csq_,
    float* __restrict__ assign_out, float* __restrict__ sum_ass,
    float* __restrict__ qx) {
  __shared__ uint xpk[TN][CH + 4];      // [n][c-chunk] packed hi|lo, 33.8 KB
  __shared__ uint cpk[PP][CH + 4];      // [p][c-chunk] packed, 16.9 KB
  __shared__ ushort xh[CC][TN + 8];     // [c][n] bf16 hi (persistent), 73.7 KB
  __shared__ ushort abf[PP][TN + 8];    // [p][n] assign bf16, 4.6 KB
  __shared__ float redacc[4][64][12];   // pair acc reduction, 12.3 KB
  __shared__ float xsqb[8][4][16];      // xsq cross-wave, 2 KB

  int tid = threadIdx.x;
  int wv = tid >> 6, lane = tid & 63;
  int l15 = lane & 15, lg = lane >> 4;
  int half = wv >> 2, wn = wv & 3;      // c-half, n-quarter
  int b = blockIdx.x >> 6;
  int n0 = (blockIdx.x & 63) * TN;

  int crow = tid >> 2;            // c row in chunk 0..127
  int nw = (tid & 3) << 4;        // n window 0,16,32,48
  int p_s = tid >> 4;             // centers staging p 0..31
  int cw = (tid & 15) << 3;       // centers staging c off 0..120

  const float* xb = x + (size_t)b * CC * NN + n0 + nw;
  const float* wb = w + (size_t)p_s * CC + cw;

  float xsqp[16];
#pragma unroll
  for (int i = 0; i < 16; ++i) xsqp[i] = 0.f;
  f32x4 acc0 = {0.f, 0.f, 0.f, 0.f}, acc1 = {0.f, 0.f, 0.f, 0.f};

  float4 xr[4], wr0, wr1;

#define LOADC(C0)                                                        \
  {                                                                      \
    _Pragma("unroll") for (int i = 0; i < 4; ++i)                        \
        xr[i] = *(const float4*)&xb[(size_t)((C0) + crow) * NN + i * 4]; \
    wr0 = *(const float4*)&wb[(C0)];                                     \
    wr1 = *(const float4*)&wb[(C0) + 4];                                 \
  }

#define WRITEC(C0)                                                       \
  {                                                                      \
    _Pragma("unroll") for (int i = 0; i < 4; ++i) {                      \
      float4 v = xr[i];                                                  \
      int nl = nw + i * 4;                                               \
      xpk[nl + 0][crow] = packbf(v.x);                                   \
      xpk[nl + 1][crow] = packbf(v.y);                                   \
      xpk[nl + 2][crow] = packbf(v.z);                                   \
      xpk[nl + 3][crow] = packbf(v.w);                                   \
      xsqp[i * 4 + 0] = fmaf(v.x, v.x, xsqp[i * 4 + 0]);                 \
      xsqp[i * 4 + 1] = fmaf(v.y, v.y, xsqp[i * 4 + 1]);                 \
      xsqp[i * 4 + 2] = fmaf(v.z, v.z, xsqp[i * 4 + 2]);                 \
      xsqp[i * 4 + 3] = fmaf(v.w, v.w, xsqp[i * 4 + 3]);                 \
      ushort4 u;                                                         \
      u.x = f2bf(v.x); u.y = f2bf(v.y);                                  \
      u.z = f2bf(v.z); u.w = f2bf(v.w);                                  \
      *(ushort4*)&xh[(C0) + crow][nl] = u;                               \
    }                                                                    \
    uint4 u0 = {packbf(wr0.x), packbf(wr0.y), packbf(wr0.z), packbf(wr0.w)}; \
    uint4 u1 = {packbf(wr1.x), packbf(wr1.y), packbf(wr1.z), packbf(wr1.w)}; \
    *(uint4*)&cpk[p_s][cw] = u0;                                         \
    *(uint4*)&cpk[p_s][cw + 4] = u1;                                     \
  }

  // prologue
  LOADC(0);
  WRITEC(0);
  __syncthreads();

  for (int c0 = 0; c0 < CC; c0 += CH) {
    bool more = (c0 + CH < CC);
    if (more) LOADC(c0 + CH);
    int cb = half * 64;
#pragma unroll
    for (int ks = 0; ks < 2; ++ks) {
      int co = cb + ks * 32 + lg * 8;
      BfPair A0 = unpack8(&cpk[l15][0], co);
      BfPair A1 = unpack8(&cpk[l15 + 16][0], co);
      BfPair B0 = unpack8(&xpk[wn * 16 + l15][0], co);
      acc0 = __builtin_amdgcn_mfma_f32_16x16x32_bf16(A0.hi, B0.hi, acc0, 0, 0, 0);
      acc1 = __builtin_amdgcn_mfma_f32_16x16x32_bf16(A1.hi, B0.hi, acc1, 0, 0, 0);
      acc0 = __builtin_amdgcn_mfma_f32_16x16x32_bf16(A0.hi, B0.lo, acc0, 0, 0, 0);
      acc1 = __builtin_amdgcn_mfma_f32_16x16x32_bf16(A1.hi, B0.lo, acc1, 0, 0, 0);
      acc0 = __builtin_amdgcn_mfma_f32_16x16x32_bf16(A0.lo, B0.hi, acc0, 0, 0, 0);
      acc1 = __builtin_amdgcn_mfma_f32_16x16x32_bf16(A1.lo, B0.hi, acc1, 0, 0, 0);
    }
    if (more) {
      __syncthreads();   // all waves done reading old chunk
      WRITEC(c0 + CH);
      __syncthreads();
    }
  }

  // ---- epilogue: xsq reduce + acc pair-reduce
#pragma unroll
  for (int i = 0; i < 16; ++i) {
    xsqp[i] += __shfl_xor(xsqp[i], 4);
    xsqp[i] += __shfl_xor(xsqp[i], 8);
    xsqp[i] += __shfl_xor(xsqp[i], 16);
    xsqp[i] += __shfl_xor(xsqp[i], 32);
  }
  if (lane < 4) {
#pragma unroll
    for (int i = 0; i < 16; ++i) xsqb[wv][lane][i] = xsqp[i];
  }
  if (half) {
    *(f32x4*)&redacc[wn][lane][0] = acc0;
    *(f32x4*)&redacc[wn][lane][4] = acc1;
  }
  __syncthreads();

  if (!half) {
    acc0 += *(const f32x4*)&redacc[wn][lane][0];
    acc1 += *(const f32x4*)&redacc[wn][lane][4];
    float xsq = 0.f;
#pragma unroll
    for (int ww = 0; ww < 8; ++ww) xsq += xsqb[ww][wn][l15];

    // logits + in-register softmax over p
    float L[2][4];
    float m = -3.4e38f;
#pragma unroll
    for (int i = 0; i < 4; ++i) {
      int pa = lg * 4 + i, pb = 16 + lg * 4 + i;
      float la = fminf(2.f * acc0[i] - xsq - csq_[pa], 0.f) * rbeta_[pa];
      float lb = fminf(2.f * acc1[i] - xsq - csq_[pb], 0.f) * rbeta_[pb];
      L[0][i] = la; L[1][i] = lb;
      m = fmaxf(m, fmaxf(la, lb));
    }
    m = fmaxf(m, __shfl_xor(m, 16));
    m = fmaxf(m, __shfl_xor(m, 32));
    float s = 0.f;
#pragma unroll
    for (int pf = 0; pf < 2; ++pf)
#pragma unroll
      for (int i = 0; i < 4; ++i) {
        float e = __expf(L[pf][i] - m);
        L[pf][i] = e;
        s += e;
      }
    s += __shfl_xor(s, 16);
    s += __shfl_xor(s, 32);
    float inv = 1.f / s;

    int nl = wn * 16 + l15;
#pragma unroll
    for (int pf = 0; pf < 2; ++pf)
#pragma unroll
      for (int i = 0; i < 4; ++i) {
        int p = pf * 16 + lg * 4 + i;
        float a = L[pf][i] * inv;
        assign_out[((size_t)b * PP + p) * NN + n0 + nl] = a;
        abf[p][nl] = f2bf(a);
        float v = a;
        v += __shfl_xor(v, 1); v += __shfl_xor(v, 2);
        v += __shfl_xor(v, 4); v += __shfl_xor(v, 8);
        if (l15 == 0) atomicAdd(&sum_ass[b * PP + p], v);
      }
  }
  __syncthreads();   // abf ready; xh ready since staging

  // ---- phase 2: qx. wave owns c in [64wv, 64wv+64).
  f32x4 q[2][4];
#pragma unroll
  for (int pf = 0; pf < 2; ++pf)
#pragma unroll
    for (int cf = 0; cf < 4; ++cf) q[pf][cf] = {0.f, 0.f, 0.f, 0.f};

  int cb2 = wv * 64;
#pragma unroll
  for (int ks = 0; ks < 2; ++ks) {
    int ko = ks * 32 + lg * 8;
    bf16x8 A0 = *(const bf16x8*)&abf[l15][ko];
    bf16x8 A1 = *(const bf16x8*)&abf[l15 + 16][ko];
#pragma unroll
    for (int cf = 0; cf < 4; ++cf) {
      bf16x8 Bv = *(const bf16x8*)&xh[cb2 + cf * 16 + l15][ko];
      q[0][cf] = __builtin_amdgcn_mfma_f32_16x16x32_bf16(A0, Bv, q[0][cf], 0, 0, 0);
      q[1][cf] = __builtin_amdgcn_mfma_f32_16x16x32_bf16(A1, Bv, q[1][cf], 0, 0, 0);
    }
  }
#pragma unroll
  for (int pf = 0; pf < 2; ++pf)
#pragma unroll
    for (int cf = 0; cf < 4; ++cf)
#pragma unroll
      for (int i = 0; i < 4; ++i) {
        int p = pf * 16 + lg * 4 + i;
        int c = cb2 + cf * 16 + l15;
        atomicAdd(&qx[((size_t)b * PP + p) * CC + c], q[pf][cf][i]);
      }
#undef LOADC
#undef WRITEC
}

// ---------------------------------------------------------------------------
// finalize: out = (qx/max(sum_ass,1e-5) - centers)/sigma ; L2-normalize;
// write transposed out_t[b][c][p]. block per (b,p), 256 threads, 2 c each.
// ---------------------------------------------------------------------------
__global__ __launch_bounds__(256) void finalize_kernel(
    const float* __restrict__ qx, const float* __restrict__ w,
    const float* __restrict__ beta, const float* __restrict__ sum_ass,
    float* __restrict__ out_t) {
  int b = blockIdx.x >> 5;
  int p = blockIdx.x & 31;
  int tid = threadIdx.x;
  int wave = tid >> 6, lane = tid & 63;

  float inv_sa = 1.f / fmaxf(sum_ass[b * PP + p], 1e-5f);
  float rsig = rsqrtf(0.5f * beta[p]);

  int c0 = tid, c1 = tid + 256;
  const float* qrow = qx + ((size_t)b * PP + p) * CC;
  const float* wrow = w + (size_t)p * CC;
  float t0 = (qrow[c0] * inv_sa - wrow[c0]) * rsig;
  float t1 = (qrow[c1] * inv_sa - wrow[c1]) * rsig;

  float nr = t0 * t0 + t1 * t1;
#pragma unroll
  for (int off = 32; off; off >>= 1) nr += __shfl_down(nr, off);
  __shared__ float red[4];
  if (lane == 0) red[wave] = nr;
  __syncthreads();
  float norm2 = red[0] + red[1] + red[2] + red[3];
  float scale = 1.f / fmaxf(sqrtf(norm2), 1e-12f);

  float* ob = out_t + (size_t)b * CC * PP + p;
  ob[(size_t)c0 * PP] = t0 * scale;
  ob[(size_t)c1 * PP] = t1 * scale;
}

// ---------------------------------------------------------------------------
extern "C" void kernel_launch(void* const* d_in, const int* in_sizes, int n_in,
                              void* d_out, int out_size, void* d_ws,
                              size_t ws_size, hipStream_t stream) {
  const float* x = (const float*)d_in[0];   // [B,C,H,W]
  const float* w = (const float*)d_in[1];   // [P,C,1,1]
  const float* sf = (const float*)d_in[2];  // [P]

  float* out_t = (float*)d_out;                  // [B,C,P]
  float* assign = out_t + (size_t)BB * CC * PP;  // [B,P,N]

  float* ws = (float*)d_ws;
  float* beta = ws;           // 32
  float* rbeta = ws + 32;     // 32
  float* csq = ws + 64;       // 32
  float* sum_ass = ws + 96;   // 512
  float* qx = ws + 608;       // B*P*C = 262144 (contiguous with sum_ass)

  // zero sum_ass + qx for atomic accumulation
  hipMemsetAsync(sum_ass, 0, (512 + (size_t)BB * PP * CC) * sizeof(float),
                 stream);
  prep_kernel<<<PP, 64, 0, stream>>>(w, sf, beta, rbeta, csq);
  fused_kernel<<<BB * 64, 512, 0, stream>>>(x, w, rbeta, csq, assign,
                                            sum_ass, qx);
  finalize_kernel<<<BB * PP, 256, 0, stream>>>(qx, w, beta, sum_ass, out_t);
}

// Round 9
// 95.366 us; speedup vs baseline: 1.7647x; 1.7647x over previous
//
#include <hip/hip_runtime.h>

constexpr int BB = 16;     // batch
constexpr int CC = 512;    // channels
constexpr int PP = 32;     // clusters
constexpr int NN = 4096;   // H*W
constexpr int TN = 128;    // n-tile per block

using f32x4 = __attribute__((ext_vector_type(4))) float;
using bf16x8 = __attribute__((ext_vector_type(8))) short;
typedef unsigned int uint;

__device__ __forceinline__ ushort f2bf(float f) {
  unsigned u = __builtin_bit_cast(unsigned, f);
  u += 0x7FFFu + ((u >> 16) & 1u);   // round-to-nearest-even
  return (ushort)(u >> 16);
}

// pack float -> (bf16_lo << 16) | bf16_hi, hi = bf16(f), lo = bf16(f - hi)
__device__ __forceinline__ uint packbf(float f) {
  uint u = __builtin_bit_cast(uint, f);
  uint hi = (u + (0x7FFFu + ((u >> 16) & 1u))) >> 16;
  float hif = __builtin_bit_cast(float, hi << 16);
  float lof = f - hif;
  uint ul = __builtin_bit_cast(uint, lof);
  uint lo = (ul + (0x7FFFu + ((ul >> 16) & 1u))) >> 16;
  return (lo << 16) | hi;
}

struct BfPair { bf16x8 hi, lo; };

__device__ __forceinline__ BfPair unpack8(const uint* __restrict__ row, int co) {
  uint4 a = *(const uint4*)(row + co);
  uint4 b = *(const uint4*)(row + co + 4);
  union { bf16x8 v; uint d[4]; } H, L;
  H.d[0] = (a.x & 0xffffu) | (a.y << 16); L.d[0] = (a.x >> 16) | (a.y & 0xffff0000u);
  H.d[1] = (a.z & 0xffffu) | (a.w << 16); L.d[1] = (a.z >> 16) | (a.w & 0xffff0000u);
  H.d[2] = (b.x & 0xffffu) | (b.y << 16); L.d[2] = (b.x >> 16) | (b.y & 0xffff0000u);
  H.d[3] = (b.z & 0xffffu) | (b.w << 16); L.d[3] = (b.z >> 16) | (b.w & 0xffff0000u);
  return {H.v, L.v};
}

// ---------------------------------------------------------------------------
// prep: beta = sigmoid(sf), rbeta = 1/beta, csq[p] = |centers_p|^2 (fp32).
// ---------------------------------------------------------------------------
__global__ __launch_bounds__(64) void prep_kernel(
    const float* __restrict__ w, const float* __restrict__ sf,
    float* __restrict__ beta, float* __restrict__ rbeta,
    float* __restrict__ csq) {
  int p = blockIdx.x;
  int t = threadIdx.x;
  float s = 0.f;
  for (int i = t; i < CC; i += 64) {
    float v = w[p * CC + i];
    s = fmaf(v, v, s);
  }
#pragma unroll
  for (int off = 32; off; off >>= 1) s += __shfl_down(s, off);
  if (t == 0) {
    csq[p] = s;
    float e = __expf(-sf[p]);
    rbeta[p] = 1.f + e;            // 1/beta
    beta[p] = 1.f / (1.f + e);     // beta
  }
}

// ---------------------------------------------------------------------------
// fused assign+qx, occupancy-preserving (46 KB LDS -> 3 blocks/CU).
// grid 512 (16 b x 32 n-tiles of 128), block 256 = 4 waves.
// Phase 1 = R7 assign verbatim: split-bf16 MFMA cx, in-register softmax,
//   assign store + sum_ass atomics; also writes assign bf16 into abf.
// Phase 2 = qx: re-read x (L3-resident) tile [c][n] bf16 into xt (ALIASES
//   the dead xpk buffer), 4 c-chunks of 128; bf16 MFMA; fp32 atomicAdd
//   into L2-resident qx[b][p][c].
// ---------------------------------------------------------------------------
__global__ __launch_bounds__(256, 3) void fused_kernel(
    const float* __restrict__ x, const float* __restrict__ w,
    const float* __restrict__ rbeta_, const float* __restrict__ csq_,
    float* __restrict__ assign_out, float* __restrict__ sum_ass,
    float* __restrict__ qx) {
  __shared__ uint xpk[128][68];       // phase1: [n][c-chunk] packed, 34.8 KB
  __shared__ uint cpk[32][68];        // phase1: [p][c-chunk] packed, 8.7 KB
  __shared__ float xsqw[4][4][32];    // xsq partials, 2 KB
  __shared__ float xsqf[128];         // xsq per n, 0.5 KB
  ushort(*xt)[136] = (ushort(*)[136]) & xpk[0][0];   // phase2 x tile alias
  ushort(*abf)[136] = (ushort(*)[136]) & cpk[0][0];  // phase2 assign alias

  int tid = threadIdx.x;
  int wv = tid >> 6, lane = tid & 63;
  int l15 = lane & 15, lg = lane >> 4;
  int b = blockIdx.x >> 5;
  int n0 = (blockIdx.x & 31) * TN;

  int c_s = tid >> 2;          // phase1 staging c row 0..63
  int q = tid & 3;             // phase1 staging n window (32 n)
  int p_s = tid >> 3;          // centers staging p 0..31
  int cq8 = (tid & 7) << 3;    // centers staging c offset 0..56

  const float* xb = x + (size_t)b * CC * NN + n0 + q * 32;
  const float* wb = w + (size_t)p_s * CC + cq8;

  f32x4 acc[2][2];
#pragma unroll
  for (int i = 0; i < 2; ++i)
#pragma unroll
    for (int j = 0; j < 2; ++j) acc[i][j] = {0.f, 0.f, 0.f, 0.f};
  float sq[32];
#pragma unroll
  for (int i = 0; i < 32; ++i) sq[i] = 0.f;

  float4 xr[8], wr0, wr1;
  // ---- phase 1 prologue: load + stage chunk 0
#pragma unroll
  for (int i = 0; i < 8; ++i)
    xr[i] = *(const float4*)&xb[(size_t)c_s * NN + i * 4];
  wr0 = *(const float4*)&wb[0];
  wr1 = *(const float4*)&wb[4];
#pragma unroll
  for (int i = 0; i < 8; ++i) {
    float4 v = xr[i];
    sq[4 * i + 0] = fmaf(v.x, v.x, sq[4 * i + 0]);
    sq[4 * i + 1] = fmaf(v.y, v.y, sq[4 * i + 1]);
    sq[4 * i + 2] = fmaf(v.z, v.z, sq[4 * i + 2]);
    sq[4 * i + 3] = fmaf(v.w, v.w, sq[4 * i + 3]);
    int nr = q * 32 + i * 4;
    xpk[nr + 0][c_s] = packbf(v.x);
    xpk[nr + 1][c_s] = packbf(v.y);
    xpk[nr + 2][c_s] = packbf(v.z);
    xpk[nr + 3][c_s] = packbf(v.w);
  }
  {
    uint4 u0 = {packbf(wr0.x), packbf(wr0.y), packbf(wr0.z), packbf(wr0.w)};
    uint4 u1 = {packbf(wr1.x), packbf(wr1.y), packbf(wr1.z), packbf(wr1.w)};
    *(uint4*)&cpk[p_s][cq8] = u0;
    *(uint4*)&cpk[p_s][cq8 + 4] = u1;
  }
  __syncthreads();

  // ---- phase 1 main loop over c-chunks of 64
  for (int c0 = 0; c0 < CC; c0 += 64) {
    bool more = (c0 + 64 < CC);
    if (more) {
#pragma unroll
      for (int i = 0; i < 8; ++i)
        xr[i] = *(const float4*)&xb[(size_t)(c0 + 64 + c_s) * NN + i * 4];
      wr0 = *(const float4*)&wb[c0 + 64];
      wr1 = *(const float4*)&wb[c0 + 64 + 4];
    }
#pragma unroll
    for (int ks = 0; ks < 2; ++ks) {
      int co = ks * 32 + lg * 8;
      BfPair A0 = unpack8(&cpk[l15][0], co);
      BfPair A1 = unpack8(&cpk[l15 + 16][0], co);
      BfPair B0 = unpack8(&xpk[wv * 32 + l15][0], co);
      BfPair B1 = unpack8(&xpk[wv * 32 + 16 + l15][0], co);
      acc[0][0] = __builtin_amdgcn_mfma_f32_16x16x32_bf16(A0.hi, B0.hi, acc[0][0], 0, 0, 0);
      acc[0][1] = __builtin_amdgcn_mfma_f32_16x16x32_bf16(A0.hi, B1.hi, acc[0][1], 0, 0, 0);
      acc[1][0] = __builtin_amdgcn_mfma_f32_16x16x32_bf16(A1.hi, B0.hi, acc[1][0], 0, 0, 0);
      acc[1][1] = __builtin_amdgcn_mfma_f32_16x16x32_bf16(A1.hi, B1.hi, acc[1][1], 0, 0, 0);
      acc[0][0] = __builtin_amdgcn_mfma_f32_16x16x32_bf16(A0.hi, B0.lo, acc[0][0], 0, 0, 0);
      acc[0][1] = __builtin_amdgcn_mfma_f32_16x16x32_bf16(A0.hi, B1.lo, acc[0][1], 0, 0, 0);
      acc[1][0] = __builtin_amdgcn_mfma_f32_16x16x32_bf16(A1.hi, B0.lo, acc[1][0], 0, 0, 0);
      acc[1][1] = __builtin_amdgcn_mfma_f32_16x16x32_bf16(A1.hi, B1.lo, acc[1][1], 0, 0, 0);
      acc[0][0] = __builtin_amdgcn_mfma_f32_16x16x32_bf16(A0.lo, B0.hi, acc[0][0], 0, 0, 0);
      acc[0][1] = __builtin_amdgcn_mfma_f32_16x16x32_bf16(A0.lo, B1.hi, acc[0][1], 0, 0, 0);
      acc[1][0] = __builtin_amdgcn_mfma_f32_16x16x32_bf16(A1.lo, B0.hi, acc[1][0], 0, 0, 0);
      acc[1][1] = __builtin_amdgcn_mfma_f32_16x16x32_bf16(A1.lo, B1.hi, acc[1][1], 0, 0, 0);
    }
    if (more) {
      __syncthreads();
#pragma unroll
      for (int i = 0; i < 8; ++i) {
        float4 v = xr[i];
        sq[4 * i + 0] = fmaf(v.x, v.x, sq[4 * i + 0]);
        sq[4 * i + 1] = fmaf(v.y, v.y, sq[4 * i + 1]);
        sq[4 * i + 2] = fmaf(v.z, v.z, sq[4 * i + 2]);
        sq[4 * i + 3] = fmaf(v.w, v.w, sq[4 * i + 3]);
        int nr = q * 32 + i * 4;
        xpk[nr + 0][c_s] = packbf(v.x);
        xpk[nr + 1][c_s] = packbf(v.y);
        xpk[nr + 2][c_s] = packbf(v.z);
        xpk[nr + 3][c_s] = packbf(v.w);
      }
      uint4 u0 = {packbf(wr0.x), packbf(wr0.y), packbf(wr0.z), packbf(wr0.w)};
      uint4 u1 = {packbf(wr1.x), packbf(wr1.y), packbf(wr1.z), packbf(wr1.w)};
      *(uint4*)&cpk[p_s][cq8] = u0;
      *(uint4*)&cpk[p_s][cq8 + 4] = u1;
      __syncthreads();
    }
  }

  // ---- xsq reduce
#pragma unroll
  for (int i = 0; i < 32; ++i) {
    sq[i] += __shfl_xor(sq[i], 4);
    sq[i] += __shfl_xor(sq[i], 8);
    sq[i] += __shfl_xor(sq[i], 16);
    sq[i] += __shfl_xor(sq[i], 32);
  }
  if ((lane >> 2) == 0) {
#pragma unroll
    for (int i = 0; i < 32; ++i) xsqw[wv][lane & 3][i] = sq[i];
  }
  __syncthreads();   // barrier 1: phase-1 LDS reads all complete past here
  if (tid < 128)
    xsqf[tid] = xsqw[0][tid >> 5][tid & 31] + xsqw[1][tid >> 5][tid & 31] +
                xsqw[2][tid >> 5][tid & 31] + xsqw[3][tid >> 5][tid & 31];
  __syncthreads();   // barrier 2

  float xsqn0 = xsqf[wv * 32 + l15];
  float xsqn1 = xsqf[wv * 32 + 16 + l15];

  float csqv[2][4], rbv[2][4];
#pragma unroll
  for (int pf = 0; pf < 2; ++pf)
#pragma unroll
    for (int i = 0; i < 4; ++i) {
      int p = pf * 16 + lg * 4 + i;
      csqv[pf][i] = csq_[p];
      rbv[pf][i] = rbeta_[p];
    }

  // logits + in-register softmax over p
  float L[2][2][4];
  float m0 = -3.4e38f, m1 = -3.4e38f;
#pragma unroll
  for (int pf = 0; pf < 2; ++pf)
#pragma unroll
    for (int i = 0; i < 4; ++i) {
      float l0 = fminf(2.f * acc[pf][0][i] - xsqn0 - csqv[pf][i], 0.f) * rbv[pf][i];
      float l1 = fminf(2.f * acc[pf][1][i] - xsqn1 - csqv[pf][i], 0.f) * rbv[pf][i];
      L[pf][0][i] = l0; L[pf][1][i] = l1;
      m0 = fmaxf(m0, l0); m1 = fmaxf(m1, l1);
    }
  m0 = fmaxf(m0, __shfl_xor(m0, 16)); m0 = fmaxf(m0, __shfl_xor(m0, 32));
  m1 = fmaxf(m1, __shfl_xor(m1, 16)); m1 = fmaxf(m1, __shfl_xor(m1, 32));
  float s0 = 0.f, s1 = 0.f;
#pragma unroll
  for (int pf = 0; pf < 2; ++pf)
#pragma unroll
    for (int i = 0; i < 4; ++i) {
      float e0 = __expf(L[pf][0][i] - m0);
      float e1 = __expf(L[pf][1][i] - m1);
      L[pf][0][i] = e0; L[pf][1][i] = e1;
      s0 += e0; s1 += e1;
    }
  s0 += __shfl_xor(s0, 16); s0 += __shfl_xor(s0, 32);
  s1 += __shfl_xor(s1, 16); s1 += __shfl_xor(s1, 32);
  float inv0 = 1.f / s0, inv1 = 1.f / s1;

  // assign store (global + abf bf16 into cpk alias) + fused sum_ass
  float* aoB = assign_out + (size_t)b * PP * NN + n0 + wv * 32 + l15;
#pragma unroll
  for (int pf = 0; pf < 2; ++pf)
#pragma unroll
    for (int i = 0; i < 4; ++i) {
      int p = pf * 16 + lg * 4 + i;
      float a0 = L[pf][0][i] * inv0;
      float a1 = L[pf][1][i] * inv1;
      aoB[(size_t)p * NN] = a0;
      aoB[(size_t)p * NN + 16] = a1;
      abf[p][wv * 32 + l15] = f2bf(a0);
      abf[p][wv * 32 + 16 + l15] = f2bf(a1);
      float v = a0 + a1;
      v += __shfl_xor(v, 1); v += __shfl_xor(v, 2);
      v += __shfl_xor(v, 4); v += __shfl_xor(v, 8);
      if (l15 == 0) atomicAdd(&sum_ass[b * PP + p], v);
    }

  // ---- phase 2: qx += a[p][n] * x[c][n] over this tile's 128 n.
  int c_s2 = tid >> 1;            // x tile row 0..127
  int nh2 = (tid & 1) << 6;       // n half 0/64
  const float* xg = x + (size_t)b * CC * NN + n0;

  for (int ch = 0; ch < 4; ++ch) {   // c-chunks of 128
    __syncthreads();   // abf/xt writers & previous chunk readers done
#pragma unroll
    for (int h = 0; h < 2; ++h) {
      float4 v[8];
#pragma unroll
      for (int i = 0; i < 8; ++i)
        v[i] = *(const float4*)&xg[(size_t)(ch * 128 + c_s2) * NN + nh2 + h * 32 + i * 4];
#pragma unroll
      for (int i = 0; i < 8; ++i) {
        ushort4 u;
        u.x = f2bf(v[i].x); u.y = f2bf(v[i].y);
        u.z = f2bf(v[i].z); u.w = f2bf(v[i].w);
        *(ushort4*)&xt[c_s2][nh2 + h * 32 + i * 4] = u;
      }
    }
    __syncthreads();

    f32x4 q2[2][2];
#pragma unroll
    for (int pf = 0; pf < 2; ++pf)
#pragma unroll
      for (int cf = 0; cf < 2; ++cf) q2[pf][cf] = {0.f, 0.f, 0.f, 0.f};
#pragma unroll
    for (int ks = 0; ks < 4; ++ks) {
      int ko = ks * 32 + lg * 8;
      bf16x8 A0 = *(const bf16x8*)&abf[l15][ko];
      bf16x8 A1 = *(const bf16x8*)&abf[l15 + 16][ko];
#pragma unroll
      for (int cf = 0; cf < 2; ++cf) {
        bf16x8 Bv = *(const bf16x8*)&xt[wv * 32 + cf * 16 + l15][ko];
        q2[0][cf] = __builtin_amdgcn_mfma_f32_16x16x32_bf16(A0, Bv, q2[0][cf], 0, 0, 0);
        q2[1][cf] = __builtin_amdgcn_mfma_f32_16x16x32_bf16(A1, Bv, q2[1][cf], 0, 0, 0);
      }
    }
#pragma unroll
    for (int pf = 0; pf < 2; ++pf)
#pragma unroll
      for (int cf = 0; cf < 2; ++cf)
#pragma unroll
        for (int i = 0; i < 4; ++i) {
          int p = pf * 16 + lg * 4 + i;
          int c = ch * 128 + wv * 32 + cf * 16 + l15;
          atomicAdd(&qx[((size_t)b * PP + p) * CC + c], q2[pf][cf][i]);
        }
  }
}

// ---------------------------------------------------------------------------
// finalize: out = (qx/max(sum_ass,1e-5) - centers)/sigma ; L2-normalize;
// write transposed out_t[b][c][p]. block per (b,p), 256 threads, 2 c each.
// ---------------------------------------------------------------------------
__global__ __launch_bounds__(256) void finalize_kernel(
    const float* __restrict__ qx, const float* __restrict__ w,
    const float* __restrict__ beta, const float* __restrict__ sum_ass,
    float* __restrict__ out_t) {
  int b = blockIdx.x >> 5;
  int p = blockIdx.x & 31;
  int tid = threadIdx.x;
  int wave = tid >> 6, lane = tid & 63;

  float inv_sa = 1.f / fmaxf(sum_ass[b * PP + p], 1e-5f);
  float rsig = rsqrtf(0.5f * beta[p]);

  int c0 = tid, c1 = tid + 256;
  const float* qrow = qx + ((size_t)b * PP + p) * CC;
  const float* wrow = w + (size_t)p * CC;
  float t0 = (qrow[c0] * inv_sa - wrow[c0]) * rsig;
  float t1 = (qrow[c1] * inv_sa - wrow[c1]) * rsig;

  float nr = t0 * t0 + t1 * t1;
#pragma unroll
  for (int off = 32; off; off >>= 1) nr += __shfl_down(nr, off);
  __shared__ float red[4];
  if (lane == 0) red[wave] = nr;
  __syncthreads();
  float norm2 = red[0] + red[1] + red[2] + red[3];
  float scale = 1.f / fmaxf(sqrtf(norm2), 1e-12f);

  float* ob = out_t + (size_t)b * CC * PP + p;
  ob[(size_t)c0 * PP] = t0 * scale;
  ob[(size_t)c1 * PP] = t1 * scale;
}

// ---------------------------------------------------------------------------
extern "C" void kernel_launch(void* const* d_in, const int* in_sizes, int n_in,
                              void* d_out, int out_size, void* d_ws,
                              size_t ws_size, hipStream_t stream) {
  const float* x = (const float*)d_in[0];   // [B,C,H,W]
  const float* w = (const float*)d_in[1];   // [P,C,1,1]
  const float* sf = (const float*)d_in[2];  // [P]

  float* out_t = (float*)d_out;                  // [B,C,P]
  float* assign = out_t + (size_t)BB * CC * PP;  // [B,P,N]

  float* ws = (float*)d_ws;
  float* beta = ws;           // 32
  float* rbeta = ws + 32;     // 32
  float* csq = ws + 64;       // 32
  float* sum_ass = ws + 96;   // 512
  float* qx = ws + 608;       // B*P*C = 262144 (contiguous with sum_ass)

  // zero sum_ass + qx for atomic accumulation
  hipMemsetAsync(sum_ass, 0, (512 + (size_t)BB * PP * CC) * sizeof(float),
                 stream);
  prep_kernel<<<PP, 64, 0, stream>>>(w, sf, beta, rbeta, csq);
  fused_kernel<<<BB * 32, 256, 0, stream>>>(x, w, rbeta, csq, assign,
                                            sum_ass, qx);
  finalize_kernel<<<BB * PP, 256, 0, stream>>>(qx, w, beta, sum_ass, out_t);
}